// Round 20
// baseline (370.282 us; speedup 1.0000x reference)
//
#include <hip/hip_runtime.h>

#define NN 50000
#define EE 800000
#define TT 12
#define BB 2

// ws layout (4B units):
//  [0, 50048)            dinv
//  [50048, 2450048)      AX[b][n][t][f]  (BB*NN*TT*2 floats)
//  [2450048, 2454144)    P folded params: per gate g at g*1120:
//          [0:32) WF0, [32:64) WF1, [64:96) cF, [96+32k+j) LB[k][j]
//        probs at [3360:3372)
//  [2454144, 2504192)    cnt (int)
//  [2504192, 2554240)    off (int)
//  [2554240, 2604288)    cur (int)
//  [2604288, 2604416)    bsum (int)
// CSR payload lives in d_out (fully overwritten by k_recur at the end):
//  d_out[0..800000)        esrc (int)
//  d_out[800000..1600000)  ewgt (float)
#define OFF_AX   50048
#define OFF_P    2450048
#define OFF_CNT  2454144
#define OFF_OFF  2504192
#define OFF_CUR  2554240
#define OFF_BSUM 2604288
#define NB_SCAN  98  // ceil(50000/512)
#define NNODES   (BB * NN)
#define NW       4      // waves per k_recur block
#define NBLK_REC 1563   // 6252 waves, ~16 nodes per wave (1 node/wave/iter)

__device__ __forceinline__ float fsig(float x) {
    x = fminf(fmaxf(x, -30.f), 30.f);
    return __builtin_amdgcn_rcpf(1.f + __expf(-x));
}
__device__ __forceinline__ float ftanh(float x) {
    x = fminf(fmaxf(x, -15.f), 15.f);
    float e = __expf(-2.f * x);
    return (1.f - e) * __builtin_amdgcn_rcpf(1.f + e);
}

__global__ void k_zero(int* __restrict__ cnt) {
    int i = blockIdx.x * 256 + threadIdx.x;
    if (i < NN) cnt[i] = 0;
}

__global__ void k_count(const int* __restrict__ idx, int* __restrict__ cnt) {
    int e = blockIdx.x * 256 + threadIdx.x;
    if (e < EE) atomicAdd(&cnt[idx[EE + e]], 1);
}

// exclusive scan of cnt -> off (per-block), block totals -> bsum
__global__ void k_scanA(const int* __restrict__ cnt, int* __restrict__ off,
                        int* __restrict__ bsum) {
    __shared__ int sm[512];
    int i = blockIdx.x * 512 + threadIdx.x;
    int v = (i < NN) ? cnt[i] : 0;
    sm[threadIdx.x] = v;
    __syncthreads();
#pragma unroll
    for (int d = 1; d < 512; d <<= 1) {
        int t = (threadIdx.x >= d) ? sm[threadIdx.x - d] : 0;
        __syncthreads();
        sm[threadIdx.x] += t;
        __syncthreads();
    }
    if (i < NN) off[i] = sm[threadIdx.x] - v;  // exclusive within block
    if (threadIdx.x == 511) bsum[blockIdx.x] = sm[511];
}

__global__ void k_scanB(int* __restrict__ bsum) {
    __shared__ int sm[128];
    int tid = threadIdx.x;
    int v = (tid < NB_SCAN) ? bsum[tid] : 0;
    sm[tid] = v;
    __syncthreads();
#pragma unroll
    for (int d = 1; d < 128; d <<= 1) {
        int t = (tid >= d) ? sm[tid - d] : 0;
        __syncthreads();
        sm[tid] += t;
        __syncthreads();
    }
    if (tid < NB_SCAN) bsum[tid] = sm[tid] - v;  // exclusive
}

__global__ void k_scanC(int* __restrict__ off, const int* __restrict__ bsum,
                        int* __restrict__ cur) {
    int i = blockIdx.x * 256 + threadIdx.x;
    if (i < NN) {
        int o = off[i] + bsum[i >> 9];
        off[i] = o;
        cur[i] = o;
    }
}

__global__ void k_fill(const int* __restrict__ idx, const float* __restrict__ w,
                       int* __restrict__ cur, int* __restrict__ esrc,
                       float* __restrict__ ewgt) {
    int e = blockIdx.x * 256 + threadIdx.x;
    if (e >= EE) return;
    int c = idx[EE + e];
    int s = atomicAdd(&cur[c], 1);
    esrc[s] = idx[e];
    ewgt[s] = w[e];
}

__global__ void k_degdinv(const int* __restrict__ off, const int* __restrict__ cnt,
                          const float* __restrict__ ewgt, float* __restrict__ dinv) {
    int n = blockIdx.x * 256 + threadIdx.x;
    if (n >= NN) return;
    int s0 = off[n], c = cnt[n];
    float d = 1.f;  // self loop
    for (int q = 0; q < c; q++) d += ewgt[s0 + q];
    dinv[n] = rsqrtf(d);
}

// AX[b][n][t][f] = dinv[n]^2 * X[b][n][f][t] + sum_in nrm * X[b][src][f][t]
__global__ __launch_bounds__(256) void k_gather(const float* __restrict__ X,
                                                const float* __restrict__ dinv,
                                                const int* __restrict__ esrc,
                                                const float* __restrict__ ewgt,
                                                const int* __restrict__ off,
                                                const int* __restrict__ cnt,
                                                float* __restrict__ AX) {
    int tid = blockIdx.x * 256 + threadIdx.x;  // b*NN + n
    if (tid >= NNODES) return;
    int b = tid / NN;
    int n = tid - b * NN;
    float di = dinv[n];
    const float* Xb = X + (size_t)b * NN * 24;

    float xf[24], acc[24];
    {
        const float4* xs = (const float4*)(Xb + (size_t)n * 24);
        float s = di * di;
#pragma unroll
        for (int q = 0; q < 6; q++) {
            float4 v = xs[q];
            xf[4 * q] = v.x; xf[4 * q + 1] = v.y; xf[4 * q + 2] = v.z; xf[4 * q + 3] = v.w;
        }
#pragma unroll
        for (int t = 0; t < TT; t++) {
            acc[2 * t] = s * xf[t];
            acc[2 * t + 1] = s * xf[12 + t];
        }
    }
    int s0 = off[n], c = cnt[n];
    for (int q = 0; q < c; q++) {
        int r = esrc[s0 + q];
        float nrm = dinv[r] * ewgt[s0 + q] * di;
        const float4* xr = (const float4*)(Xb + (size_t)r * 24);
#pragma unroll
        for (int p = 0; p < 6; p++) {
            float4 v = xr[p];
            xf[4 * p] = v.x; xf[4 * p + 1] = v.y; xf[4 * p + 2] = v.z; xf[4 * p + 3] = v.w;
        }
#pragma unroll
        for (int t = 0; t < TT; t++) {
            acc[2 * t] = fmaf(nrm, xf[t], acc[2 * t]);
            acc[2 * t + 1] = fmaf(nrm, xf[12 + t], acc[2 * t + 1]);
        }
    }
    float4* o = (float4*)(AX + (size_t)tid * 24);
#pragma unroll
    for (int q = 0; q < 6; q++)
        o[q] = make_float4(acc[4 * q], acc[4 * q + 1], acc[4 * q + 2], acc[4 * q + 3]);
}

// fold weights: per gate g at base g*1120: WF0[j]=sum_k W[0][k]Lw[k][j], WF1, cF, LB[k][j]=Lw[32+k][j]
__global__ void k_fold(const float* __restrict__ Wz, const float* __restrict__ bz,
                       const float* __restrict__ Lwz, const float* __restrict__ Lbz,
                       const float* __restrict__ Wr, const float* __restrict__ br,
                       const float* __restrict__ Lwr, const float* __restrict__ Lbr,
                       const float* __restrict__ Wh, const float* __restrict__ bh,
                       const float* __restrict__ Lwh, const float* __restrict__ Lbh,
                       const float* __restrict__ att, float* __restrict__ P) {
    int tid = threadIdx.x;
    if (tid < 96) {
        int g = tid >> 5, j = tid & 31;
        const float* W  = g == 0 ? Wz  : (g == 1 ? Wr  : Wh);
        const float* b  = g == 0 ? bz  : (g == 1 ? br  : bh);
        const float* Lw = g == 0 ? Lwz : (g == 1 ? Lwr : Lwh);
        const float* Lb = g == 0 ? Lbz : (g == 1 ? Lbr : Lbh);
        float* out = P + g * 1120;
        float w0 = 0.f, w1 = 0.f, c = 0.f;
        for (int k = 0; k < 32; k++) {
            float lw = Lw[k * 32 + j];
            w0 += W[k] * lw;
            w1 += W[32 + k] * lw;
            c  += b[k] * lw;
        }
        out[j] = w0;
        out[32 + j] = w1;
        out[64 + j] = c + Lb[j];
        for (int k = 0; k < 32; k++) out[96 + k * 32 + j] = Lw[(32 + k) * 32 + j];
    } else if (tid == 96) {
        float m = -1e30f;
        for (int t = 0; t < TT; t++) m = fmaxf(m, att[t]);
        float s = 0.f;
        float e[TT];
        for (int t = 0; t < TT; t++) { e[t] = __expf(att[t] - m); s += e[t]; }
        for (int t = 0; t < TT; t++) P[3360 + t] = e[t] / s;
    }
}

// k-split j-per-lane recurrence: ONE node per wave; lane = (h,j), h=lane>>5.
// Each lane holds only LB[k in 16h..16h+16)][j] for the 3 gates = 48 weights
// (+9 WF/cF) -> fits the ~84-128 arch-VGPR budget, killing the AGPR-shuttle
// inflation seen in R11-R18 (required 96+ weights vs 84 granted -> ~4.8x VALU
// inflation, 183us plateau). Halves combine 16-term partials with one
// __shfl_xor(.,32) (permlane32_swap). Waves are independent; no barriers.
__global__ __launch_bounds__(256) void k_recur(const float* __restrict__ AX,
                                               const float* __restrict__ P,
                                               float* __restrict__ out) {
    __shared__ __align__(16) float Hs[NW][32];
    __shared__ __align__(16) float rHs[NW][32];
    __shared__ __align__(16) float AXs[NW][24];
    const int lane = threadIdx.x & 63;
    const int w = threadIdx.x >> 6;       // wave id in block
    const int j = lane & 31;
    const int h = lane >> 5;              // k-strip half
    const int k0 = h * 16;
    const int gwave = blockIdx.x * NW + w;

    // per-lane weight strip (loop-invariant): 16 k-values per gate
    float LBz[16], LBr[16], LBh[16];
    float wz0 = P[j],        wz1 = P[32 + j],        cz = P[64 + j];
    float wr0 = P[1120 + j], wr1 = P[1120 + 32 + j], cr = P[1120 + 64 + j];
    float wh0 = P[2240 + j], wh1 = P[2240 + 32 + j], ch = P[2240 + 64 + j];
#pragma unroll
    for (int k = 0; k < 16; k++) {
        LBz[k] = P[96 + (k0 + k) * 32 + j];
        LBr[k] = P[1120 + 96 + (k0 + k) * 32 + j];
        LBh[k] = P[2240 + 96 + (k0 + k) * 32 + j];
    }

#pragma unroll 1
    for (int node = gwave; node < NNODES; node += NBLK_REC * NW) {
        if (lane < 24) AXs[w][lane] = AX[(size_t)node * 24 + lane];
        // same-wave lockstep: lgkmcnt ordering suffices, no barrier

        // t = 0: H == 0 -> z/h init-only, rH == 0.
        float2 a = *(const float2*)&AXs[w][0];
        float z = fsig(fmaf(a.x, wz0, fmaf(a.y, wz1, cz)));
        float th = ftanh(fmaf(a.x, wh0, fmaf(a.y, wh1, ch)));
        float H = (1.f - z) * th;   // redundant on both halves
        float acc = P[3360] * H;
        if (lane < 32) Hs[w][j] = H;

#pragma unroll 1
        for (int t = 1; t < TT; t++) {
            a = *(const float2*)&AXs[w][2 * t];
            // read own k-strip of H (4 x b128)
            float hb[16];
#pragma unroll
            for (int i = 0; i < 4; i++) {
                float4 v = *(const float4*)&Hs[w][k0 + 4 * i];
                hb[4 * i] = v.x; hb[4 * i + 1] = v.y;
                hb[4 * i + 2] = v.z; hb[4 * i + 3] = v.w;
            }
            // r gate partial + combine
            float sr;
            {
                float s0 = 0.f, s1 = 0.f, s2 = 0.f, s3 = 0.f;
#pragma unroll
                for (int k = 0; k < 16; k += 4) {
                    s0 = fmaf(hb[k],     LBr[k],     s0);
                    s1 = fmaf(hb[k + 1], LBr[k + 1], s1);
                    s2 = fmaf(hb[k + 2], LBr[k + 2], s2);
                    s3 = fmaf(hb[k + 3], LBr[k + 3], s3);
                }
                sr = (s0 + s1) + (s2 + s3);
            }
            sr += __shfl_xor(sr, 32, 64);
            float rH = fsig(fmaf(a.x, wr0, fmaf(a.y, wr1, cr)) + sr) * H;
            if (lane < 32) rHs[w][j] = rH;
            // z gate partial + combine (reuses hb)
            float sz;
            {
                float s0 = 0.f, s1 = 0.f, s2 = 0.f, s3 = 0.f;
#pragma unroll
                for (int k = 0; k < 16; k += 4) {
                    s0 = fmaf(hb[k],     LBz[k],     s0);
                    s1 = fmaf(hb[k + 1], LBz[k + 1], s1);
                    s2 = fmaf(hb[k + 2], LBz[k + 2], s2);
                    s3 = fmaf(hb[k + 3], LBz[k + 3], s3);
                }
                sz = (s0 + s1) + (s2 + s3);
            }
            sz += __shfl_xor(sz, 32, 64);
            z = fsig(fmaf(a.x, wz0, fmaf(a.y, wz1, cz)) + sz);
            // read own k-strip of rH, h gate partial + combine
            float rb[16];
#pragma unroll
            for (int i = 0; i < 4; i++) {
                float4 v = *(const float4*)&rHs[w][k0 + 4 * i];
                rb[4 * i] = v.x; rb[4 * i + 1] = v.y;
                rb[4 * i + 2] = v.z; rb[4 * i + 3] = v.w;
            }
            float sh;
            {
                float s0 = 0.f, s1 = 0.f, s2 = 0.f, s3 = 0.f;
#pragma unroll
                for (int k = 0; k < 16; k += 4) {
                    s0 = fmaf(rb[k],     LBh[k],     s0);
                    s1 = fmaf(rb[k + 1], LBh[k + 1], s1);
                    s2 = fmaf(rb[k + 2], LBh[k + 2], s2);
                    s3 = fmaf(rb[k + 3], LBh[k + 3], s3);
                }
                sh = (s0 + s1) + (s2 + s3);
            }
            sh += __shfl_xor(sh, 32, 64);
            th = ftanh(fmaf(a.x, wh0, fmaf(a.y, wh1, ch)) + sh);
            float Hn = fmaf(z, H - th, th);  // z*H + (1-z)*th
            H = Hn;
            acc = fmaf(P[3360 + t], Hn, acc);
            if (lane < 32 && t < TT - 1) Hs[w][j] = Hn;
        }
        if (lane < 32) out[(size_t)node * 32 + j] = acc;
    }
}

extern "C" void kernel_launch(void* const* d_in, const int* in_sizes, int n_in,
                              void* d_out, int out_size, void* d_ws, size_t ws_size,
                              hipStream_t stream) {
    const float* X   = (const float*)d_in[0];
    const int*   idx = (const int*)d_in[1];
    const float* ew  = (const float*)d_in[2];
    const float* Wz  = (const float*)d_in[3];
    const float* bz  = (const float*)d_in[4];
    const float* Wr  = (const float*)d_in[5];
    const float* br  = (const float*)d_in[6];
    const float* Wh  = (const float*)d_in[7];
    const float* bh  = (const float*)d_in[8];
    const float* Lwz = (const float*)d_in[9];
    const float* Lbz = (const float*)d_in[10];
    const float* Lwr = (const float*)d_in[11];
    const float* Lbr = (const float*)d_in[12];
    const float* Lwh = (const float*)d_in[13];
    const float* Lbh = (const float*)d_in[14];
    const float* att = (const float*)d_in[15];

    float* ws   = (float*)d_ws;
    float* dinv = ws;
    float* AX   = ws + OFF_AX;
    float* P    = ws + OFF_P;
    int*   cnt  = (int*)ws + OFF_CNT;
    int*   off  = (int*)ws + OFF_OFF;
    int*   cur  = (int*)ws + OFF_CUR;
    int*   bsum = (int*)ws + OFF_BSUM;
    float* out  = (float*)d_out;
    int*   esrc = (int*)d_out;              // scratch inside d_out
    float* ewgt = (float*)d_out + EE;       // scratch inside d_out

    hipLaunchKernelGGL(k_zero, dim3((NN + 255) / 256), dim3(256), 0, stream, cnt);
    hipLaunchKernelGGL(k_count, dim3((EE + 255) / 256), dim3(256), 0, stream, idx, cnt);
    hipLaunchKernelGGL(k_scanA, dim3(NB_SCAN), dim3(512), 0, stream, cnt, off, bsum);
    hipLaunchKernelGGL(k_scanB, dim3(1), dim3(128), 0, stream, bsum);
    hipLaunchKernelGGL(k_scanC, dim3((NN + 255) / 256), dim3(256), 0, stream, off, bsum, cur);
    hipLaunchKernelGGL(k_fill, dim3((EE + 255) / 256), dim3(256), 0, stream, idx, ew, cur, esrc, ewgt);
    hipLaunchKernelGGL(k_degdinv, dim3((NN + 255) / 256), dim3(256), 0, stream, off, cnt, ewgt, dinv);
    hipLaunchKernelGGL(k_gather, dim3((NNODES + 255) / 256), dim3(256), 0, stream,
                       X, dinv, esrc, ewgt, off, cnt, AX);
    hipLaunchKernelGGL(k_fold, dim3(1), dim3(128), 0, stream,
                       Wz, bz, Lwz, Lbz, Wr, br, Lwr, Lbr, Wh, bh, Lwh, Lbh, att, P);
    hipLaunchKernelGGL(k_recur, dim3(NBLK_REC), dim3(256), 0, stream, AX, P, out);
}

// Round 21
// 335.232 us; speedup vs baseline: 1.1046x; 1.1046x over previous
//
#include <hip/hip_runtime.h>

#define NN 50000
#define EE 800000
#define TT 12
#define BB 2

// ws layout (4B units):
//  [0, 50048)            dinv
//  [50048, 2450048)      AX[b][n][t][f]  (BB*NN*TT*2 floats)
//  [2450048, 2454144)    P folded params: per gate g at g*1120:
//          [0:32) WF0, [32:64) WF1, [64:96) cF, [96+32k+j) LB[k][j]
//        probs at [3360:3372)
//  [2454144, 2504192)    cnt (int)
//  [2504192, 2554240)    off (int)
//  [2554240, 2604288)    cur (int)
//  [2604288, 2604416)    bsum (int)
// CSR payload lives in d_out (fully overwritten by k_recur at the end):
//  d_out[0..800000)        esrc (int)
//  d_out[800000..1600000)  ewgt (float)
#define OFF_AX   50048
#define OFF_P    2450048
#define OFF_CNT  2454144
#define OFF_OFF  2504192
#define OFF_CUR  2554240
#define OFF_BSUM 2604288
#define NB_SCAN  98  // ceil(50000/512)
#define NNODES   (BB * NN)
#define NW       4      // waves per k_recur block
#define NBLK_REC 6250   // 25000 waves (~24 queued/SIMD, ~10 resident at VGPR=48),
                        // 4 nodes/wave. R20 ran 6252 waves -> only ~3 resident/SIMD,
                        // latency-bound at per-SIMD duty ~36% (95.6% CU-level VALUBusy
                        // is "any SIMD"). More waves = in-phase stall coverage.

__device__ __forceinline__ float fsig(float x) {
    x = fminf(fmaxf(x, -30.f), 30.f);
    return __builtin_amdgcn_rcpf(1.f + __expf(-x));
}
__device__ __forceinline__ float ftanh(float x) {
    x = fminf(fmaxf(x, -15.f), 15.f);
    float e = __expf(-2.f * x);
    return (1.f - e) * __builtin_amdgcn_rcpf(1.f + e);
}

__global__ void k_zero(int* __restrict__ cnt) {
    int i = blockIdx.x * 256 + threadIdx.x;
    if (i < NN) cnt[i] = 0;
}

__global__ void k_count(const int* __restrict__ idx, int* __restrict__ cnt) {
    int e = blockIdx.x * 256 + threadIdx.x;
    if (e < EE) atomicAdd(&cnt[idx[EE + e]], 1);
}

// exclusive scan of cnt -> off (per-block), block totals -> bsum
__global__ void k_scanA(const int* __restrict__ cnt, int* __restrict__ off,
                        int* __restrict__ bsum) {
    __shared__ int sm[512];
    int i = blockIdx.x * 512 + threadIdx.x;
    int v = (i < NN) ? cnt[i] : 0;
    sm[threadIdx.x] = v;
    __syncthreads();
#pragma unroll
    for (int d = 1; d < 512; d <<= 1) {
        int t = (threadIdx.x >= d) ? sm[threadIdx.x - d] : 0;
        __syncthreads();
        sm[threadIdx.x] += t;
        __syncthreads();
    }
    if (i < NN) off[i] = sm[threadIdx.x] - v;  // exclusive within block
    if (threadIdx.x == 511) bsum[blockIdx.x] = sm[511];
}

__global__ void k_scanB(int* __restrict__ bsum) {
    __shared__ int sm[128];
    int tid = threadIdx.x;
    int v = (tid < NB_SCAN) ? bsum[tid] : 0;
    sm[tid] = v;
    __syncthreads();
#pragma unroll
    for (int d = 1; d < 128; d <<= 1) {
        int t = (tid >= d) ? sm[tid - d] : 0;
        __syncthreads();
        sm[tid] += t;
        __syncthreads();
    }
    if (tid < NB_SCAN) bsum[tid] = sm[tid] - v;  // exclusive
}

__global__ void k_scanC(int* __restrict__ off, const int* __restrict__ bsum,
                        int* __restrict__ cur) {
    int i = blockIdx.x * 256 + threadIdx.x;
    if (i < NN) {
        int o = off[i] + bsum[i >> 9];
        off[i] = o;
        cur[i] = o;
    }
}

__global__ void k_fill(const int* __restrict__ idx, const float* __restrict__ w,
                       int* __restrict__ cur, int* __restrict__ esrc,
                       float* __restrict__ ewgt) {
    int e = blockIdx.x * 256 + threadIdx.x;
    if (e >= EE) return;
    int c = idx[EE + e];
    int s = atomicAdd(&cur[c], 1);
    esrc[s] = idx[e];
    ewgt[s] = w[e];
}

__global__ void k_degdinv(const int* __restrict__ off, const int* __restrict__ cnt,
                          const float* __restrict__ ewgt, float* __restrict__ dinv) {
    int n = blockIdx.x * 256 + threadIdx.x;
    if (n >= NN) return;
    int s0 = off[n], c = cnt[n];
    float d = 1.f;  // self loop
    for (int q = 0; q < c; q++) d += ewgt[s0 + q];
    dinv[n] = rsqrtf(d);
}

// AX[b][n][t][f] = dinv[n]^2 * X[b][n][f][t] + sum_in nrm * X[b][src][f][t]
__global__ __launch_bounds__(256) void k_gather(const float* __restrict__ X,
                                                const float* __restrict__ dinv,
                                                const int* __restrict__ esrc,
                                                const float* __restrict__ ewgt,
                                                const int* __restrict__ off,
                                                const int* __restrict__ cnt,
                                                float* __restrict__ AX) {
    int tid = blockIdx.x * 256 + threadIdx.x;  // b*NN + n
    if (tid >= NNODES) return;
    int b = tid / NN;
    int n = tid - b * NN;
    float di = dinv[n];
    const float* Xb = X + (size_t)b * NN * 24;

    float xf[24], acc[24];
    {
        const float4* xs = (const float4*)(Xb + (size_t)n * 24);
        float s = di * di;
#pragma unroll
        for (int q = 0; q < 6; q++) {
            float4 v = xs[q];
            xf[4 * q] = v.x; xf[4 * q + 1] = v.y; xf[4 * q + 2] = v.z; xf[4 * q + 3] = v.w;
        }
#pragma unroll
        for (int t = 0; t < TT; t++) {
            acc[2 * t] = s * xf[t];
            acc[2 * t + 1] = s * xf[12 + t];
        }
    }
    int s0 = off[n], c = cnt[n];
    for (int q = 0; q < c; q++) {
        int r = esrc[s0 + q];
        float nrm = dinv[r] * ewgt[s0 + q] * di;
        const float4* xr = (const float4*)(Xb + (size_t)r * 24);
#pragma unroll
        for (int p = 0; p < 6; p++) {
            float4 v = xr[p];
            xf[4 * p] = v.x; xf[4 * p + 1] = v.y; xf[4 * p + 2] = v.z; xf[4 * p + 3] = v.w;
        }
#pragma unroll
        for (int t = 0; t < TT; t++) {
            acc[2 * t] = fmaf(nrm, xf[t], acc[2 * t]);
            acc[2 * t + 1] = fmaf(nrm, xf[12 + t], acc[2 * t + 1]);
        }
    }
    float4* o = (float4*)(AX + (size_t)tid * 24);
#pragma unroll
    for (int q = 0; q < 6; q++)
        o[q] = make_float4(acc[4 * q], acc[4 * q + 1], acc[4 * q + 2], acc[4 * q + 3]);
}

// fold weights: per gate g at base g*1120: WF0[j]=sum_k W[0][k]Lw[k][j], WF1, cF, LB[k][j]=Lw[32+k][j]
__global__ void k_fold(const float* __restrict__ Wz, const float* __restrict__ bz,
                       const float* __restrict__ Lwz, const float* __restrict__ Lbz,
                       const float* __restrict__ Wr, const float* __restrict__ br,
                       const float* __restrict__ Lwr, const float* __restrict__ Lbr,
                       const float* __restrict__ Wh, const float* __restrict__ bh,
                       const float* __restrict__ Lwh, const float* __restrict__ Lbh,
                       const float* __restrict__ att, float* __restrict__ P) {
    int tid = threadIdx.x;
    if (tid < 96) {
        int g = tid >> 5, j = tid & 31;
        const float* W  = g == 0 ? Wz  : (g == 1 ? Wr  : Wh);
        const float* b  = g == 0 ? bz  : (g == 1 ? br  : bh);
        const float* Lw = g == 0 ? Lwz : (g == 1 ? Lwr : Lwh);
        const float* Lb = g == 0 ? Lbz : (g == 1 ? Lbr : Lbh);
        float* out = P + g * 1120;
        float w0 = 0.f, w1 = 0.f, c = 0.f;
        for (int k = 0; k < 32; k++) {
            float lw = Lw[k * 32 + j];
            w0 += W[k] * lw;
            w1 += W[32 + k] * lw;
            c  += b[k] * lw;
        }
        out[j] = w0;
        out[32 + j] = w1;
        out[64 + j] = c + Lb[j];
        for (int k = 0; k < 32; k++) out[96 + k * 32 + j] = Lw[(32 + k) * 32 + j];
    } else if (tid == 96) {
        float m = -1e30f;
        for (int t = 0; t < TT; t++) m = fmaxf(m, att[t]);
        float s = 0.f;
        float e[TT];
        for (int t = 0; t < TT; t++) { e[t] = __expf(att[t] - m); s += e[t]; }
        for (int t = 0; t < TT; t++) P[3360 + t] = e[t] / s;
    }
}

// k-split j-per-lane recurrence: ONE node per wave; lane = (h,j), h=lane>>5.
// Each lane holds LB[k in 16h..16h+16)][j] for the 3 gates = 48 weights (+9)
// -> VGPR 48, up to ~10 waves/SIMD resident. Halves combine 16-term partials
// with one __shfl_xor(.,32). Waves independent; no barriers.
__global__ __launch_bounds__(256) void k_recur(const float* __restrict__ AX,
                                               const float* __restrict__ P,
                                               float* __restrict__ out) {
    __shared__ __align__(16) float Hs[NW][32];
    __shared__ __align__(16) float rHs[NW][32];
    __shared__ __align__(16) float AXs[NW][24];
    const int lane = threadIdx.x & 63;
    const int w = threadIdx.x >> 6;       // wave id in block
    const int j = lane & 31;
    const int h = lane >> 5;              // k-strip half
    const int k0 = h * 16;
    const int gwave = blockIdx.x * NW + w;

    // per-lane weight strip (loop-invariant): 16 k-values per gate
    float LBz[16], LBr[16], LBh[16];
    float wz0 = P[j],        wz1 = P[32 + j],        cz = P[64 + j];
    float wr0 = P[1120 + j], wr1 = P[1120 + 32 + j], cr = P[1120 + 64 + j];
    float wh0 = P[2240 + j], wh1 = P[2240 + 32 + j], ch = P[2240 + 64 + j];
#pragma unroll
    for (int k = 0; k < 16; k++) {
        LBz[k] = P[96 + (k0 + k) * 32 + j];
        LBr[k] = P[1120 + 96 + (k0 + k) * 32 + j];
        LBh[k] = P[2240 + 96 + (k0 + k) * 32 + j];
    }

#pragma unroll 1
    for (int node = gwave; node < NNODES; node += NBLK_REC * NW) {
        if (lane < 24) AXs[w][lane] = AX[(size_t)node * 24 + lane];
        // same-wave lockstep: lgkmcnt ordering suffices, no barrier

        // t = 0: H == 0 -> z/h init-only, rH == 0.
        float2 a = *(const float2*)&AXs[w][0];
        float z = fsig(fmaf(a.x, wz0, fmaf(a.y, wz1, cz)));
        float th = ftanh(fmaf(a.x, wh0, fmaf(a.y, wh1, ch)));
        float H = (1.f - z) * th;   // redundant on both halves
        float acc = P[3360] * H;
        if (lane < 32) Hs[w][j] = H;

#pragma unroll 1
        for (int t = 1; t < TT; t++) {
            a = *(const float2*)&AXs[w][2 * t];
            // read own k-strip of H (4 x b128)
            float hb[16];
#pragma unroll
            for (int i = 0; i < 4; i++) {
                float4 v = *(const float4*)&Hs[w][k0 + 4 * i];
                hb[4 * i] = v.x; hb[4 * i + 1] = v.y;
                hb[4 * i + 2] = v.z; hb[4 * i + 3] = v.w;
            }
            // r gate partial + combine
            float sr;
            {
                float s0 = 0.f, s1 = 0.f, s2 = 0.f, s3 = 0.f;
#pragma unroll
                for (int k = 0; k < 16; k += 4) {
                    s0 = fmaf(hb[k],     LBr[k],     s0);
                    s1 = fmaf(hb[k + 1], LBr[k + 1], s1);
                    s2 = fmaf(hb[k + 2], LBr[k + 2], s2);
                    s3 = fmaf(hb[k + 3], LBr[k + 3], s3);
                }
                sr = (s0 + s1) + (s2 + s3);
            }
            sr += __shfl_xor(sr, 32, 64);
            float rH = fsig(fmaf(a.x, wr0, fmaf(a.y, wr1, cr)) + sr) * H;
            if (lane < 32) rHs[w][j] = rH;
            // z gate partial + combine (reuses hb)
            float sz;
            {
                float s0 = 0.f, s1 = 0.f, s2 = 0.f, s3 = 0.f;
#pragma unroll
                for (int k = 0; k < 16; k += 4) {
                    s0 = fmaf(hb[k],     LBz[k],     s0);
                    s1 = fmaf(hb[k + 1], LBz[k + 1], s1);
                    s2 = fmaf(hb[k + 2], LBz[k + 2], s2);
                    s3 = fmaf(hb[k + 3], LBz[k + 3], s3);
                }
                sz = (s0 + s1) + (s2 + s3);
            }
            sz += __shfl_xor(sz, 32, 64);
            z = fsig(fmaf(a.x, wz0, fmaf(a.y, wz1, cz)) + sz);
            // read own k-strip of rH, h gate partial + combine
            float rb[16];
#pragma unroll
            for (int i = 0; i < 4; i++) {
                float4 v = *(const float4*)&rHs[w][k0 + 4 * i];
                rb[4 * i] = v.x; rb[4 * i + 1] = v.y;
                rb[4 * i + 2] = v.z; rb[4 * i + 3] = v.w;
            }
            float sh;
            {
                float s0 = 0.f, s1 = 0.f, s2 = 0.f, s3 = 0.f;
#pragma unroll
                for (int k = 0; k < 16; k += 4) {
                    s0 = fmaf(rb[k],     LBh[k],     s0);
                    s1 = fmaf(rb[k + 1], LBh[k + 1], s1);
                    s2 = fmaf(rb[k + 2], LBh[k + 2], s2);
                    s3 = fmaf(rb[k + 3], LBh[k + 3], s3);
                }
                sh = (s0 + s1) + (s2 + s3);
            }
            sh += __shfl_xor(sh, 32, 64);
            th = ftanh(fmaf(a.x, wh0, fmaf(a.y, wh1, ch)) + sh);
            float Hn = fmaf(z, H - th, th);  // z*H + (1-z)*th
            H = Hn;
            acc = fmaf(P[3360 + t], Hn, acc);
            if (lane < 32 && t < TT - 1) Hs[w][j] = Hn;
        }
        if (lane < 32) out[(size_t)node * 32 + j] = acc;
    }
}

extern "C" void kernel_launch(void* const* d_in, const int* in_sizes, int n_in,
                              void* d_out, int out_size, void* d_ws, size_t ws_size,
                              hipStream_t stream) {
    const float* X   = (const float*)d_in[0];
    const int*   idx = (const int*)d_in[1];
    const float* ew  = (const float*)d_in[2];
    const float* Wz  = (const float*)d_in[3];
    const float* bz  = (const float*)d_in[4];
    const float* Wr  = (const float*)d_in[5];
    const float* br  = (const float*)d_in[6];
    const float* Wh  = (const float*)d_in[7];
    const float* bh  = (const float*)d_in[8];
    const float* Lwz = (const float*)d_in[9];
    const float* Lbz = (const float*)d_in[10];
    const float* Lwr = (const float*)d_in[11];
    const float* Lbr = (const float*)d_in[12];
    const float* Lwh = (const float*)d_in[13];
    const float* Lbh = (const float*)d_in[14];
    const float* att = (const float*)d_in[15];

    float* ws   = (float*)d_ws;
    float* dinv = ws;
    float* AX   = ws + OFF_AX;
    float* P    = ws + OFF_P;
    int*   cnt  = (int*)ws + OFF_CNT;
    int*   off  = (int*)ws + OFF_OFF;
    int*   cur  = (int*)ws + OFF_CUR;
    int*   bsum = (int*)ws + OFF_BSUM;
    float* out  = (float*)d_out;
    int*   esrc = (int*)d_out;              // scratch inside d_out
    float* ewgt = (float*)d_out + EE;       // scratch inside d_out

    hipLaunchKernelGGL(k_zero, dim3((NN + 255) / 256), dim3(256), 0, stream, cnt);
    hipLaunchKernelGGL(k_count, dim3((EE + 255) / 256), dim3(256), 0, stream, idx, cnt);
    hipLaunchKernelGGL(k_scanA, dim3(NB_SCAN), dim3(512), 0, stream, cnt, off, bsum);
    hipLaunchKernelGGL(k_scanB, dim3(1), dim3(128), 0, stream, bsum);
    hipLaunchKernelGGL(k_scanC, dim3((NN + 255) / 256), dim3(256), 0, stream, off, bsum, cur);
    hipLaunchKernelGGL(k_fill, dim3((EE + 255) / 256), dim3(256), 0, stream, idx, ew, cur, esrc, ewgt);
    hipLaunchKernelGGL(k_degdinv, dim3((NN + 255) / 256), dim3(256), 0, stream, off, cnt, ewgt, dinv);
    hipLaunchKernelGGL(k_gather, dim3((NNODES + 255) / 256), dim3(256), 0, stream,
                       X, dinv, esrc, ewgt, off, cnt, AX);
    hipLaunchKernelGGL(k_fold, dim3(1), dim3(128), 0, stream,
                       Wz, bz, Lwz, Lbz, Wr, br, Lwr, Lbr, Wh, bh, Lwh, Lbh, att, P);
    hipLaunchKernelGGL(k_recur, dim3(NBLK_REC), dim3(256), 0, stream, AX, P, out);
}

// Round 24
// 331.421 us; speedup vs baseline: 1.1173x; 1.0115x over previous
//
#include <hip/hip_runtime.h>

#define NN 50000
#define EE 800000
#define TT 12
#define BB 2

// ws layout (4B units):
//  [0, 50048)            dinv
//  [50048, 2450048)      AX[b][n][t][f]  (BB*NN*TT*2 floats)
//  [2450048, 2454144)    P folded params: per gate g at g*1120:
//          [0:32) WF0, [32:64) WF1, [64:96) cF, [96+32k+j) LB[k][j]
//        probs at [3360:3372)
//  [2454144, 2504192)    cnt (int)
//  [2504192, 2554240)    off (int)
//  [2554240, 2604288)    cur (int)
//  [2604288, 2604416)    bsum (int)
// CSR payload lives in d_out (fully overwritten by k_recur at the end):
//  d_out[0..1600000) as int2 epack[800000] = {src, float_bits(w)}
#define OFF_AX   50048
#define OFF_P    2450048
#define OFF_CNT  2454144
#define OFF_OFF  2504192
#define OFF_CUR  2554240
#define OFF_BSUM 2604288
#define NB_SCAN  98  // ceil(50000/512)
#define NNODES   (BB * NN)
#define NW       8      // waves per k_recur block (test block-count residency cap)
#define NBLK_REC 3125   // 3125 x 8 = 25000 waves, 4 nodes/wave (same as R21)

__device__ __forceinline__ float fsig(float x) {
    x = fminf(fmaxf(x, -30.f), 30.f);
    return __builtin_amdgcn_rcpf(1.f + __expf(-x));
}
__device__ __forceinline__ float ftanh(float x) {
    x = fminf(fmaxf(x, -15.f), 15.f);
    float e = __expf(-2.f * x);
    return (1.f - e) * __builtin_amdgcn_rcpf(1.f + e);
}

__global__ void k_count(const int* __restrict__ idx, int* __restrict__ cnt) {
    int e = blockIdx.x * 256 + threadIdx.x;
    if (e < EE) atomicAdd(&cnt[idx[EE + e]], 1);
}

// exclusive scan of cnt -> off (per-block), block totals -> bsum
__global__ void k_scanA(const int* __restrict__ cnt, int* __restrict__ off,
                        int* __restrict__ bsum) {
    __shared__ int sm[512];
    int i = blockIdx.x * 512 + threadIdx.x;
    int v = (i < NN) ? cnt[i] : 0;
    sm[threadIdx.x] = v;
    __syncthreads();
#pragma unroll
    for (int d = 1; d < 512; d <<= 1) {
        int t = (threadIdx.x >= d) ? sm[threadIdx.x - d] : 0;
        __syncthreads();
        sm[threadIdx.x] += t;
        __syncthreads();
    }
    if (i < NN) off[i] = sm[threadIdx.x] - v;  // exclusive within block
    if (threadIdx.x == 511) bsum[blockIdx.x] = sm[511];
}

__global__ void k_scanB(int* __restrict__ bsum) {
    __shared__ int sm[128];
    int tid = threadIdx.x;
    int v = (tid < NB_SCAN) ? bsum[tid] : 0;
    sm[tid] = v;
    __syncthreads();
#pragma unroll
    for (int d = 1; d < 128; d <<= 1) {
        int t = (tid >= d) ? sm[tid - d] : 0;
        __syncthreads();
        sm[tid] += t;
        __syncthreads();
    }
    if (tid < NB_SCAN) bsum[tid] = sm[tid] - v;  // exclusive
}

__global__ void k_scanC(int* __restrict__ off, const int* __restrict__ bsum,
                        int* __restrict__ cur) {
    int i = blockIdx.x * 256 + threadIdx.x;
    if (i < NN) {
        int o = off[i] + bsum[i >> 9];
        off[i] = o;
        cur[i] = o;
    }
}

// packed CSR fill: one 8B store per edge {src, float_bits(w)}
__global__ void k_fill(const int* __restrict__ idx, const float* __restrict__ w,
                       int* __restrict__ cur, int2* __restrict__ epack) {
    int e = blockIdx.x * 256 + threadIdx.x;
    if (e >= EE) return;
    int c = idx[EE + e];
    int s = atomicAdd(&cur[c], 1);
    epack[s] = make_int2(idx[e], __float_as_int(w[e]));
}

__global__ void k_degdinv(const int* __restrict__ off, const int* __restrict__ cnt,
                          const int2* __restrict__ epack, float* __restrict__ dinv) {
    int n = blockIdx.x * 256 + threadIdx.x;
    if (n >= NN) return;
    int s0 = off[n], c = cnt[n];
    float d = 1.f;  // self loop
    for (int q = 0; q < c; q++) d += __int_as_float(epack[s0 + q].y);
    dinv[n] = rsqrtf(d);
}

// AX[b][n][t][f] = dinv[n]^2 * X[b][n][f][t] + sum_in nrm * X[b][src][f][t]
// 64-thread blocks -> 1563 blocks spread over 256 CUs (256-thread blocks gave
// only 391 blocks = 1.5/CU -> latency-bound, the R2 grid-shape mistake).
__global__ __launch_bounds__(64) void k_gather(const float* __restrict__ X,
                                               const float* __restrict__ dinv,
                                               const int2* __restrict__ epack,
                                               const int* __restrict__ off,
                                               const int* __restrict__ cnt,
                                               float* __restrict__ AX) {
    int tid = blockIdx.x * 64 + threadIdx.x;  // b*NN + n
    if (tid >= NNODES) return;
    int b = tid / NN;
    int n = tid - b * NN;
    float di = dinv[n];
    const float* Xb = X + (size_t)b * NN * 24;

    float xf[24], acc[24];
    {
        const float4* xs = (const float4*)(Xb + (size_t)n * 24);
        float s = di * di;
#pragma unroll
        for (int q = 0; q < 6; q++) {
            float4 v = xs[q];
            xf[4 * q] = v.x; xf[4 * q + 1] = v.y; xf[4 * q + 2] = v.z; xf[4 * q + 3] = v.w;
        }
#pragma unroll
        for (int t = 0; t < TT; t++) {
            acc[2 * t] = s * xf[t];
            acc[2 * t + 1] = s * xf[12 + t];
        }
    }
    int s0 = off[n], c = cnt[n];
    for (int q = 0; q < c; q++) {
        int2 ep = epack[s0 + q];
        int r = ep.x;
        float nrm = dinv[r] * __int_as_float(ep.y) * di;
        const float4* xr = (const float4*)(Xb + (size_t)r * 24);
#pragma unroll
        for (int p = 0; p < 6; p++) {
            float4 v = xr[p];
            xf[4 * p] = v.x; xf[4 * p + 1] = v.y; xf[4 * p + 2] = v.z; xf[4 * p + 3] = v.w;
        }
#pragma unroll
        for (int t = 0; t < TT; t++) {
            acc[2 * t] = fmaf(nrm, xf[t], acc[2 * t]);
            acc[2 * t + 1] = fmaf(nrm, xf[12 + t], acc[2 * t + 1]);
        }
    }
    float4* o = (float4*)(AX + (size_t)tid * 24);
#pragma unroll
    for (int q = 0; q < 6; q++)
        o[q] = make_float4(acc[4 * q], acc[4 * q + 1], acc[4 * q + 2], acc[4 * q + 3]);
}

// fold weights: per gate g at base g*1120: WF0[j]=sum_k W[0][k]Lw[k][j], WF1, cF, LB[k][j]=Lw[32+k][j]
__global__ void k_fold(const float* __restrict__ Wz, const float* __restrict__ bz,
                       const float* __restrict__ Lwz, const float* __restrict__ Lbz,
                       const float* __restrict__ Wr, const float* __restrict__ br,
                       const float* __restrict__ Lwr, const float* __restrict__ Lbr,
                       const float* __restrict__ Wh, const float* __restrict__ bh,
                       const float* __restrict__ Lwh, const float* __restrict__ Lbh,
                       const float* __restrict__ att, float* __restrict__ P) {
    int tid = threadIdx.x;
    if (tid < 96) {
        int g = tid >> 5, j = tid & 31;
        const float* W  = g == 0 ? Wz  : (g == 1 ? Wr  : Wh);
        const float* b  = g == 0 ? bz  : (g == 1 ? br  : bh);
        const float* Lw = g == 0 ? Lwz : (g == 1 ? Lwr : Lwh);
        const float* Lb = g == 0 ? Lbz : (g == 1 ? Lbr : Lbh);
        float* out = P + g * 1120;
        float w0 = 0.f, w1 = 0.f, c = 0.f;
        for (int k = 0; k < 32; k++) {
            float lw = Lw[k * 32 + j];
            w0 += W[k] * lw;
            w1 += W[32 + k] * lw;
            c  += b[k] * lw;
        }
        out[j] = w0;
        out[32 + j] = w1;
        out[64 + j] = c + Lb[j];
        for (int k = 0; k < 32; k++) out[96 + k * 32 + j] = Lw[(32 + k) * 32 + j];
    } else if (tid == 96) {
        float m = -1e30f;
        for (int t = 0; t < TT; t++) m = fmaxf(m, att[t]);
        float s = 0.f;
        float e[TT];
        for (int t = 0; t < TT; t++) { e[t] = __expf(att[t] - m); s += e[t]; }
        for (int t = 0; t < TT; t++) P[3360 + t] = e[t] / s;
    }
}

// k-split j-per-lane recurrence (R21 structure, 183us): one node per wave,
// lane=(h,j); 48 weights/lane; halves combine via __shfl_xor(.,32).
// NW=8 (512-thread blocks) probes whether the ~16-waves/CU residency cap is
// block-count-based: if yes -> 32 waves/CU -> faster; if waves-based -> 183us.
__global__ __launch_bounds__(512) void k_recur(const float* __restrict__ AX,
                                               const float* __restrict__ P,
                                               float* __restrict__ out) {
    __shared__ __align__(16) float Hs[NW][32];
    __shared__ __align__(16) float rHs[NW][32];
    __shared__ __align__(16) float AXs[NW][24];
    const int lane = threadIdx.x & 63;
    const int w = threadIdx.x >> 6;       // wave id in block
    const int j = lane & 31;
    const int h = lane >> 5;              // k-strip half
    const int k0 = h * 16;
    const int gwave = blockIdx.x * NW + w;

    // per-lane weight strip (loop-invariant): 16 k-values per gate
    float LBz[16], LBr[16], LBh[16];
    float wz0 = P[j],        wz1 = P[32 + j],        cz = P[64 + j];
    float wr0 = P[1120 + j], wr1 = P[1120 + 32 + j], cr = P[1120 + 64 + j];
    float wh0 = P[2240 + j], wh1 = P[2240 + 32 + j], ch = P[2240 + 64 + j];
#pragma unroll
    for (int k = 0; k < 16; k++) {
        LBz[k] = P[96 + (k0 + k) * 32 + j];
        LBr[k] = P[1120 + 96 + (k0 + k) * 32 + j];
        LBh[k] = P[2240 + 96 + (k0 + k) * 32 + j];
    }

#pragma unroll 1
    for (int node = gwave; node < NNODES; node += NBLK_REC * NW) {
        if (lane < 24) AXs[w][lane] = AX[(size_t)node * 24 + lane];
        // same-wave lockstep: lgkmcnt ordering suffices, no barrier

        // t = 0: H == 0 -> z/h init-only, rH == 0.
        float2 a = *(const float2*)&AXs[w][0];
        float z = fsig(fmaf(a.x, wz0, fmaf(a.y, wz1, cz)));
        float th = ftanh(fmaf(a.x, wh0, fmaf(a.y, wh1, ch)));
        float H = (1.f - z) * th;   // redundant on both halves
        float acc = P[3360] * H;
        if (lane < 32) Hs[w][j] = H;

#pragma unroll 1
        for (int t = 1; t < TT; t++) {
            a = *(const float2*)&AXs[w][2 * t];
            // read own k-strip of H (4 x b128)
            float hb[16];
#pragma unroll
            for (int i = 0; i < 4; i++) {
                float4 v = *(const float4*)&Hs[w][k0 + 4 * i];
                hb[4 * i] = v.x; hb[4 * i + 1] = v.y;
                hb[4 * i + 2] = v.z; hb[4 * i + 3] = v.w;
            }
            // r gate partial + combine
            float sr;
            {
                float s0 = 0.f, s1 = 0.f, s2 = 0.f, s3 = 0.f;
#pragma unroll
                for (int k = 0; k < 16; k += 4) {
                    s0 = fmaf(hb[k],     LBr[k],     s0);
                    s1 = fmaf(hb[k + 1], LBr[k + 1], s1);
                    s2 = fmaf(hb[k + 2], LBr[k + 2], s2);
                    s3 = fmaf(hb[k + 3], LBr[k + 3], s3);
                }
                sr = (s0 + s1) + (s2 + s3);
            }
            sr += __shfl_xor(sr, 32, 64);
            float rH = fsig(fmaf(a.x, wr0, fmaf(a.y, wr1, cr)) + sr) * H;
            if (lane < 32) rHs[w][j] = rH;
            // z gate partial + combine (reuses hb)
            float sz;
            {
                float s0 = 0.f, s1 = 0.f, s2 = 0.f, s3 = 0.f;
#pragma unroll
                for (int k = 0; k < 16; k += 4) {
                    s0 = fmaf(hb[k],     LBz[k],     s0);
                    s1 = fmaf(hb[k + 1], LBz[k + 1], s1);
                    s2 = fmaf(hb[k + 2], LBz[k + 2], s2);
                    s3 = fmaf(hb[k + 3], LBz[k + 3], s3);
                }
                sz = (s0 + s1) + (s2 + s3);
            }
            sz += __shfl_xor(sz, 32, 64);
            z = fsig(fmaf(a.x, wz0, fmaf(a.y, wz1, cz)) + sz);
            // read own k-strip of rH, h gate partial + combine
            float rb[16];
#pragma unroll
            for (int i = 0; i < 4; i++) {
                float4 v = *(const float4*)&rHs[w][k0 + 4 * i];
                rb[4 * i] = v.x; rb[4 * i + 1] = v.y;
                rb[4 * i + 2] = v.z; rb[4 * i + 3] = v.w;
            }
            float sh;
            {
                float s0 = 0.f, s1 = 0.f, s2 = 0.f, s3 = 0.f;
#pragma unroll
                for (int k = 0; k < 16; k += 4) {
                    s0 = fmaf(rb[k],     LBh[k],     s0);
                    s1 = fmaf(rb[k + 1], LBh[k + 1], s1);
                    s2 = fmaf(rb[k + 2], LBh[k + 2], s2);
                    s3 = fmaf(rb[k + 3], LBh[k + 3], s3);
                }
                sh = (s0 + s1) + (s2 + s3);
            }
            sh += __shfl_xor(sh, 32, 64);
            th = ftanh(fmaf(a.x, wh0, fmaf(a.y, wh1, ch)) + sh);
            float Hn = fmaf(z, H - th, th);  // z*H + (1-z)*th
            H = Hn;
            acc = fmaf(P[3360 + t], Hn, acc);
            if (lane < 32 && t < TT - 1) Hs[w][j] = Hn;
        }
        if (lane < 32) out[(size_t)node * 32 + j] = acc;
    }
}

extern "C" void kernel_launch(void* const* d_in, const int* in_sizes, int n_in,
                              void* d_out, int out_size, void* d_ws, size_t ws_size,
                              hipStream_t stream) {
    const float* X   = (const float*)d_in[0];
    const int*   idx = (const int*)d_in[1];
    const float* ew  = (const float*)d_in[2];
    const float* Wz  = (const float*)d_in[3];
    const float* bz  = (const float*)d_in[4];
    const float* Wr  = (const float*)d_in[5];
    const float* br  = (const float*)d_in[6];
    const float* Wh  = (const float*)d_in[7];
    const float* bh  = (const float*)d_in[8];
    const float* Lwz = (const float*)d_in[9];
    const float* Lbz = (const float*)d_in[10];
    const float* Lwr = (const float*)d_in[11];
    const float* Lbr = (const float*)d_in[12];
    const float* Lwh = (const float*)d_in[13];
    const float* Lbh = (const float*)d_in[14];
    const float* att = (const float*)d_in[15];

    float* ws   = (float*)d_ws;
    float* dinv = ws;
    float* AX   = ws + OFF_AX;
    float* P    = ws + OFF_P;
    int*   cnt  = (int*)ws + OFF_CNT;
    int*   off  = (int*)ws + OFF_OFF;
    int*   cur  = (int*)ws + OFF_CUR;
    int*   bsum = (int*)ws + OFF_BSUM;
    float* out  = (float*)d_out;
    int2*  epack = (int2*)d_out;            // packed CSR scratch inside d_out

    hipMemsetAsync(cnt, 0, NN * sizeof(int), stream);
    hipLaunchKernelGGL(k_count, dim3((EE + 255) / 256), dim3(256), 0, stream, idx, cnt);
    hipLaunchKernelGGL(k_scanA, dim3(NB_SCAN), dim3(512), 0, stream, cnt, off, bsum);
    hipLaunchKernelGGL(k_scanB, dim3(1), dim3(128), 0, stream, bsum);
    hipLaunchKernelGGL(k_scanC, dim3((NN + 255) / 256), dim3(256), 0, stream, off, bsum, cur);
    hipLaunchKernelGGL(k_fill, dim3((EE + 255) / 256), dim3(256), 0, stream, idx, ew, cur, epack);
    hipLaunchKernelGGL(k_degdinv, dim3((NN + 255) / 256), dim3(256), 0, stream, off, cnt, epack, dinv);
    hipLaunchKernelGGL(k_gather, dim3((NNODES + 63) / 64), dim3(64), 0, stream,
                       X, dinv, epack, off, cnt, AX);
    hipLaunchKernelGGL(k_fold, dim3(1), dim3(128), 0, stream,
                       Wz, bz, Lwz, Lbz, Wr, br, Lwr, Lbr, Wh, bh, Lwh, Lbh, att, P);
    hipLaunchKernelGGL(k_recur, dim3(NBLK_REC), dim3(512), 0, stream, AX, P, out);
}

// Round 25
// 319.448 us; speedup vs baseline: 1.1591x; 1.0375x over previous
//
#include <hip/hip_runtime.h>

#define NN 50000
#define EE 800000
#define TT 12
#define BB 2

// ws layout (4B units):
//  [0, 50048)            dinv
//  [50048, 2450048)      AX[b][n][t][f]  (BB*NN*TT*2 floats)
//  [2450048, 2454144)    P folded params: per gate g at g*1120:
//          [0:32) WF0, [32:64) WF1, [64:96) cF, [96+32k+j) LB[k][j]
//        probs at [3360:3372)
//  [2454144, 2504192)    cnt (int)
//  [2504192, 2554240)    off (int)
//  [2554240, 2604288)    cur (int)
//  [2604288, 2604416)    bsum (int)
// CSR payload lives in d_out (fully overwritten by k_recur at the end):
//  d_out[0..1600000) as int2 epack[800000] = {src, float_bits(w)}
#define OFF_AX   50048
#define OFF_P    2450048
#define OFF_CNT  2454144
#define OFF_OFF  2504192
#define OFF_CUR  2554240
#define OFF_BSUM 2604288
#define NB_SCAN  98  // ceil(50000/512)
#define NNODES   (BB * NN)
#define NW       4      // waves per k_recur block (R24: NW=8 hurt, cap is per-wave)
#define NBLK_REC 12500  // 50000 waves, 2 nodes/wave (R20->R21: fewer nodes/wave
                        // monotonically helped 217->183; push to 2)

__device__ __forceinline__ float fsig(float x) {
    x = fminf(fmaxf(x, -30.f), 30.f);
    return __builtin_amdgcn_rcpf(1.f + __expf(-x));
}
__device__ __forceinline__ float ftanh(float x) {
    x = fminf(fmaxf(x, -15.f), 15.f);
    float e = __expf(-2.f * x);
    return (1.f - e) * __builtin_amdgcn_rcpf(1.f + e);
}

__global__ void k_count(const int* __restrict__ idx, int* __restrict__ cnt) {
    int e = blockIdx.x * 256 + threadIdx.x;
    if (e < EE) atomicAdd(&cnt[idx[EE + e]], 1);
}

// exclusive scan of cnt -> off (per-block), block totals -> bsum
__global__ void k_scanA(const int* __restrict__ cnt, int* __restrict__ off,
                        int* __restrict__ bsum) {
    __shared__ int sm[512];
    int i = blockIdx.x * 512 + threadIdx.x;
    int v = (i < NN) ? cnt[i] : 0;
    sm[threadIdx.x] = v;
    __syncthreads();
#pragma unroll
    for (int d = 1; d < 512; d <<= 1) {
        int t = (threadIdx.x >= d) ? sm[threadIdx.x - d] : 0;
        __syncthreads();
        sm[threadIdx.x] += t;
        __syncthreads();
    }
    if (i < NN) off[i] = sm[threadIdx.x] - v;  // exclusive within block
    if (threadIdx.x == 511) bsum[blockIdx.x] = sm[511];
}

__global__ void k_scanB(int* __restrict__ bsum) {
    __shared__ int sm[128];
    int tid = threadIdx.x;
    int v = (tid < NB_SCAN) ? bsum[tid] : 0;
    sm[tid] = v;
    __syncthreads();
#pragma unroll
    for (int d = 1; d < 128; d <<= 1) {
        int t = (tid >= d) ? sm[tid - d] : 0;
        __syncthreads();
        sm[tid] += t;
        __syncthreads();
    }
    if (tid < NB_SCAN) bsum[tid] = sm[tid] - v;  // exclusive
}

__global__ void k_scanC(int* __restrict__ off, const int* __restrict__ bsum,
                        int* __restrict__ cur) {
    int i = blockIdx.x * 256 + threadIdx.x;
    if (i < NN) {
        int o = off[i] + bsum[i >> 9];
        off[i] = o;
        cur[i] = o;
    }
}

// packed CSR fill: one 8B store per edge {src, float_bits(w)}
__global__ void k_fill(const int* __restrict__ idx, const float* __restrict__ w,
                       int* __restrict__ cur, int2* __restrict__ epack) {
    int e = blockIdx.x * 256 + threadIdx.x;
    if (e >= EE) return;
    int c = idx[EE + e];
    int s = atomicAdd(&cur[c], 1);
    epack[s] = make_int2(idx[e], __float_as_int(w[e]));
}

__global__ void k_degdinv(const int* __restrict__ off, const int* __restrict__ cnt,
                          const int2* __restrict__ epack, float* __restrict__ dinv) {
    int n = blockIdx.x * 256 + threadIdx.x;
    if (n >= NN) return;
    int s0 = off[n], c = cnt[n];
    float d = 1.f;  // self loop
    for (int q = 0; q < c; q++) d += __int_as_float(epack[s0 + q].y);
    dinv[n] = rsqrtf(d);
}

// AX[b][n][t][f] = dinv[n]^2 * X[b][n][f][t] + sum_in nrm * X[b][src][f][t]
__global__ __launch_bounds__(64) void k_gather(const float* __restrict__ X,
                                               const float* __restrict__ dinv,
                                               const int2* __restrict__ epack,
                                               const int* __restrict__ off,
                                               const int* __restrict__ cnt,
                                               float* __restrict__ AX) {
    int tid = blockIdx.x * 64 + threadIdx.x;  // b*NN + n
    if (tid >= NNODES) return;
    int b = tid / NN;
    int n = tid - b * NN;
    float di = dinv[n];
    const float* Xb = X + (size_t)b * NN * 24;

    float xf[24], acc[24];
    {
        const float4* xs = (const float4*)(Xb + (size_t)n * 24);
        float s = di * di;
#pragma unroll
        for (int q = 0; q < 6; q++) {
            float4 v = xs[q];
            xf[4 * q] = v.x; xf[4 * q + 1] = v.y; xf[4 * q + 2] = v.z; xf[4 * q + 3] = v.w;
        }
#pragma unroll
        for (int t = 0; t < TT; t++) {
            acc[2 * t] = s * xf[t];
            acc[2 * t + 1] = s * xf[12 + t];
        }
    }
    int s0 = off[n], c = cnt[n];
    for (int q = 0; q < c; q++) {
        int2 ep = epack[s0 + q];
        int r = ep.x;
        float nrm = dinv[r] * __int_as_float(ep.y) * di;
        const float4* xr = (const float4*)(Xb + (size_t)r * 24);
#pragma unroll
        for (int p = 0; p < 6; p++) {
            float4 v = xr[p];
            xf[4 * p] = v.x; xf[4 * p + 1] = v.y; xf[4 * p + 2] = v.z; xf[4 * p + 3] = v.w;
        }
#pragma unroll
        for (int t = 0; t < TT; t++) {
            acc[2 * t] = fmaf(nrm, xf[t], acc[2 * t]);
            acc[2 * t + 1] = fmaf(nrm, xf[12 + t], acc[2 * t + 1]);
        }
    }
    float4* o = (float4*)(AX + (size_t)tid * 24);
#pragma unroll
    for (int q = 0; q < 6; q++)
        o[q] = make_float4(acc[4 * q], acc[4 * q + 1], acc[4 * q + 2], acc[4 * q + 3]);
}

// fold weights: per gate g at base g*1120: WF0[j]=sum_k W[0][k]Lw[k][j], WF1, cF, LB[k][j]=Lw[32+k][j]
__global__ void k_fold(const float* __restrict__ Wz, const float* __restrict__ bz,
                       const float* __restrict__ Lwz, const float* __restrict__ Lbz,
                       const float* __restrict__ Wr, const float* __restrict__ br,
                       const float* __restrict__ Lwr, const float* __restrict__ Lbr,
                       const float* __restrict__ Wh, const float* __restrict__ bh,
                       const float* __restrict__ Lwh, const float* __restrict__ Lbh,
                       const float* __restrict__ att, float* __restrict__ P) {
    int tid = threadIdx.x;
    if (tid < 96) {
        int g = tid >> 5, j = tid & 31;
        const float* W  = g == 0 ? Wz  : (g == 1 ? Wr  : Wh);
        const float* b  = g == 0 ? bz  : (g == 1 ? br  : bh);
        const float* Lw = g == 0 ? Lwz : (g == 1 ? Lwr : Lwh);
        const float* Lb = g == 0 ? Lbz : (g == 1 ? Lbr : Lbh);
        float* out = P + g * 1120;
        float w0 = 0.f, w1 = 0.f, c = 0.f;
        for (int k = 0; k < 32; k++) {
            float lw = Lw[k * 32 + j];
            w0 += W[k] * lw;
            w1 += W[32 + k] * lw;
            c  += b[k] * lw;
        }
        out[j] = w0;
        out[32 + j] = w1;
        out[64 + j] = c + Lb[j];
        for (int k = 0; k < 32; k++) out[96 + k * 32 + j] = Lw[(32 + k) * 32 + j];
    } else if (tid == 96) {
        float m = -1e30f;
        for (int t = 0; t < TT; t++) m = fmaxf(m, att[t]);
        float s = 0.f;
        float e[TT];
        for (int t = 0; t < TT; t++) { e[t] = __expf(att[t] - m); s += e[t]; }
        for (int t = 0; t < TT; t++) P[3360 + t] = e[t] / s;
    }
}

// k-split j-per-lane recurrence (R21 structure): one node per wave, lane=(h,j);
// 48 weights/lane; halves combine via __shfl_xor(.,32). NW=4, 50000 waves,
// 2 nodes/wave (deepest latency coverage of the serial per-t chain).
__global__ __launch_bounds__(256) void k_recur(const float* __restrict__ AX,
                                               const float* __restrict__ P,
                                               float* __restrict__ out) {
    __shared__ __align__(16) float Hs[NW][32];
    __shared__ __align__(16) float rHs[NW][32];
    __shared__ __align__(16) float AXs[NW][24];
    const int lane = threadIdx.x & 63;
    const int w = threadIdx.x >> 6;       // wave id in block
    const int j = lane & 31;
    const int h = lane >> 5;              // k-strip half
    const int k0 = h * 16;
    const int gwave = blockIdx.x * NW + w;

    // per-lane weight strip (loop-invariant): 16 k-values per gate
    float LBz[16], LBr[16], LBh[16];
    float wz0 = P[j],        wz1 = P[32 + j],        cz = P[64 + j];
    float wr0 = P[1120 + j], wr1 = P[1120 + 32 + j], cr = P[1120 + 64 + j];
    float wh0 = P[2240 + j], wh1 = P[2240 + 32 + j], ch = P[2240 + 64 + j];
#pragma unroll
    for (int k = 0; k < 16; k++) {
        LBz[k] = P[96 + (k0 + k) * 32 + j];
        LBr[k] = P[1120 + 96 + (k0 + k) * 32 + j];
        LBh[k] = P[2240 + 96 + (k0 + k) * 32 + j];
    }

#pragma unroll 1
    for (int node = gwave; node < NNODES; node += NBLK_REC * NW) {
        if (lane < 24) AXs[w][lane] = AX[(size_t)node * 24 + lane];
        // same-wave lockstep: lgkmcnt ordering suffices, no barrier

        // t = 0: H == 0 -> z/h init-only, rH == 0.
        float2 a = *(const float2*)&AXs[w][0];
        float z = fsig(fmaf(a.x, wz0, fmaf(a.y, wz1, cz)));
        float th = ftanh(fmaf(a.x, wh0, fmaf(a.y, wh1, ch)));
        float H = (1.f - z) * th;   // redundant on both halves
        float acc = P[3360] * H;
        if (lane < 32) Hs[w][j] = H;

#pragma unroll 1
        for (int t = 1; t < TT; t++) {
            a = *(const float2*)&AXs[w][2 * t];
            // read own k-strip of H (4 x b128)
            float hb[16];
#pragma unroll
            for (int i = 0; i < 4; i++) {
                float4 v = *(const float4*)&Hs[w][k0 + 4 * i];
                hb[4 * i] = v.x; hb[4 * i + 1] = v.y;
                hb[4 * i + 2] = v.z; hb[4 * i + 3] = v.w;
            }
            // r gate partial + combine
            float sr;
            {
                float s0 = 0.f, s1 = 0.f, s2 = 0.f, s3 = 0.f;
#pragma unroll
                for (int k = 0; k < 16; k += 4) {
                    s0 = fmaf(hb[k],     LBr[k],     s0);
                    s1 = fmaf(hb[k + 1], LBr[k + 1], s1);
                    s2 = fmaf(hb[k + 2], LBr[k + 2], s2);
                    s3 = fmaf(hb[k + 3], LBr[k + 3], s3);
                }
                sr = (s0 + s1) + (s2 + s3);
            }
            sr += __shfl_xor(sr, 32, 64);
            float rH = fsig(fmaf(a.x, wr0, fmaf(a.y, wr1, cr)) + sr) * H;
            if (lane < 32) rHs[w][j] = rH;
            // z gate partial + combine (reuses hb)
            float sz;
            {
                float s0 = 0.f, s1 = 0.f, s2 = 0.f, s3 = 0.f;
#pragma unroll
                for (int k = 0; k < 16; k += 4) {
                    s0 = fmaf(hb[k],     LBz[k],     s0);
                    s1 = fmaf(hb[k + 1], LBz[k + 1], s1);
                    s2 = fmaf(hb[k + 2], LBz[k + 2], s2);
                    s3 = fmaf(hb[k + 3], LBz[k + 3], s3);
                }
                sz = (s0 + s1) + (s2 + s3);
            }
            sz += __shfl_xor(sz, 32, 64);
            z = fsig(fmaf(a.x, wz0, fmaf(a.y, wz1, cz)) + sz);
            // read own k-strip of rH, h gate partial + combine
            float rb[16];
#pragma unroll
            for (int i = 0; i < 4; i++) {
                float4 v = *(const float4*)&rHs[w][k0 + 4 * i];
                rb[4 * i] = v.x; rb[4 * i + 1] = v.y;
                rb[4 * i + 2] = v.z; rb[4 * i + 3] = v.w;
            }
            float sh;
            {
                float s0 = 0.f, s1 = 0.f, s2 = 0.f, s3 = 0.f;
#pragma unroll
                for (int k = 0; k < 16; k += 4) {
                    s0 = fmaf(rb[k],     LBh[k],     s0);
                    s1 = fmaf(rb[k + 1], LBh[k + 1], s1);
                    s2 = fmaf(rb[k + 2], LBh[k + 2], s2);
                    s3 = fmaf(rb[k + 3], LBh[k + 3], s3);
                }
                sh = (s0 + s1) + (s2 + s3);
            }
            sh += __shfl_xor(sh, 32, 64);
            th = ftanh(fmaf(a.x, wh0, fmaf(a.y, wh1, ch)) + sh);
            float Hn = fmaf(z, H - th, th);  // z*H + (1-z)*th
            H = Hn;
            acc = fmaf(P[3360 + t], Hn, acc);
            if (lane < 32 && t < TT - 1) Hs[w][j] = Hn;
        }
        if (lane < 32) out[(size_t)node * 32 + j] = acc;
    }
}

extern "C" void kernel_launch(void* const* d_in, const int* in_sizes, int n_in,
                              void* d_out, int out_size, void* d_ws, size_t ws_size,
                              hipStream_t stream) {
    const float* X   = (const float*)d_in[0];
    const int*   idx = (const int*)d_in[1];
    const float* ew  = (const float*)d_in[2];
    const float* Wz  = (const float*)d_in[3];
    const float* bz  = (const float*)d_in[4];
    const float* Wr  = (const float*)d_in[5];
    const float* br  = (const float*)d_in[6];
    const float* Wh  = (const float*)d_in[7];
    const float* bh  = (const float*)d_in[8];
    const float* Lwz = (const float*)d_in[9];
    const float* Lbz = (const float*)d_in[10];
    const float* Lwr = (const float*)d_in[11];
    const float* Lbr = (const float*)d_in[12];
    const float* Lwh = (const float*)d_in[13];
    const float* Lbh = (const float*)d_in[14];
    const float* att = (const float*)d_in[15];

    float* ws   = (float*)d_ws;
    float* dinv = ws;
    float* AX   = ws + OFF_AX;
    float* P    = ws + OFF_P;
    int*   cnt  = (int*)ws + OFF_CNT;
    int*   off  = (int*)ws + OFF_OFF;
    int*   cur  = (int*)ws + OFF_CUR;
    int*   bsum = (int*)ws + OFF_BSUM;
    float* out  = (float*)d_out;
    int2*  epack = (int2*)d_out;            // packed CSR scratch inside d_out

    hipMemsetAsync(cnt, 0, NN * sizeof(int), stream);
    hipLaunchKernelGGL(k_count, dim3((EE + 255) / 256), dim3(256), 0, stream, idx, cnt);
    hipLaunchKernelGGL(k_scanA, dim3(NB_SCAN), dim3(512), 0, stream, cnt, off, bsum);
    hipLaunchKernelGGL(k_scanB, dim3(1), dim3(128), 0, stream, bsum);
    hipLaunchKernelGGL(k_scanC, dim3((NN + 255) / 256), dim3(256), 0, stream, off, bsum, cur);
    hipLaunchKernelGGL(k_fill, dim3((EE + 255) / 256), dim3(256), 0, stream, idx, ew, cur, epack);
    hipLaunchKernelGGL(k_degdinv, dim3((NN + 255) / 256), dim3(256), 0, stream, off, cnt, epack, dinv);
    hipLaunchKernelGGL(k_gather, dim3((NNODES + 63) / 64), dim3(64), 0, stream,
                       X, dinv, epack, off, cnt, AX);
    hipLaunchKernelGGL(k_fold, dim3(1), dim3(128), 0, stream,
                       Wz, bz, Lwz, Lbz, Wr, br, Lwr, Lbr, Wh, bh, Lwh, Lbh, att, P);
    hipLaunchKernelGGL(k_recur, dim3(NBLK_REC), dim3(256), 0, stream, AX, P, out);
}

// Round 26
// 315.188 us; speedup vs baseline: 1.1748x; 1.0135x over previous
//
#include <hip/hip_runtime.h>

#define NN 50000
#define EE 800000
#define TT 12
#define BB 2

// ws layout (4B units):
//  [0, 50048)            dinv
//  [50048, 2450048)      AX[b][n][t][f]  (BB*NN*TT*2 floats)
//  [2450048, 2454144)    P folded params: per gate g at g*1120:
//          [0:32) WF0, [32:64) WF1, [64:96) cF, [96+32k+j) LB[k][j]
//        probs at [3360:3372)
//  [2454144, 2504192)    cnt (int)
//  [2504192, 2554240)    off (int)
//  [2554240, 2604288)    cur (int)
//  [2604288, 2604416)    bsum (int)
// CSR payload lives in d_out (fully overwritten by k_recur at the end):
//  d_out[0..1600000) as int2 epack[800000] = {src, float_bits(w)}
#define OFF_AX   50048
#define OFF_P    2450048
#define OFF_CNT  2454144
#define OFF_OFF  2504192
#define OFF_CUR  2554240
#define OFF_BSUM 2604288
#define NB_SCAN  98  // ceil(50000/512)
#define NNODES   (BB * NN)
#define NW       4      // waves per k_recur block
#define NBLK_REC 12500  // 12500 x 4 = 50000 waves; each wave = 1 node-PAIR,
                        // both nodes computed CONCURRENTLY (ILP covers the
                        // serial per-t chain that capped R25 at 179us)

__device__ __forceinline__ float fsig(float x) {
    x = fminf(fmaxf(x, -30.f), 30.f);
    return __builtin_amdgcn_rcpf(1.f + __expf(-x));
}
__device__ __forceinline__ float ftanh(float x) {
    x = fminf(fmaxf(x, -15.f), 15.f);
    float e = __expf(-2.f * x);
    return (1.f - e) * __builtin_amdgcn_rcpf(1.f + e);
}

__global__ void k_count(const int* __restrict__ idx, int* __restrict__ cnt) {
    int e = blockIdx.x * 256 + threadIdx.x;
    if (e < EE) atomicAdd(&cnt[idx[EE + e]], 1);
}

// exclusive scan of cnt -> off (per-block), block totals -> bsum
__global__ void k_scanA(const int* __restrict__ cnt, int* __restrict__ off,
                        int* __restrict__ bsum) {
    __shared__ int sm[512];
    int i = blockIdx.x * 512 + threadIdx.x;
    int v = (i < NN) ? cnt[i] : 0;
    sm[threadIdx.x] = v;
    __syncthreads();
#pragma unroll
    for (int d = 1; d < 512; d <<= 1) {
        int t = (threadIdx.x >= d) ? sm[threadIdx.x - d] : 0;
        __syncthreads();
        sm[threadIdx.x] += t;
        __syncthreads();
    }
    if (i < NN) off[i] = sm[threadIdx.x] - v;  // exclusive within block
    if (threadIdx.x == 511) bsum[blockIdx.x] = sm[511];
}

__global__ void k_scanB(int* __restrict__ bsum) {
    __shared__ int sm[128];
    int tid = threadIdx.x;
    int v = (tid < NB_SCAN) ? bsum[tid] : 0;
    sm[tid] = v;
    __syncthreads();
#pragma unroll
    for (int d = 1; d < 128; d <<= 1) {
        int t = (tid >= d) ? sm[tid - d] : 0;
        __syncthreads();
        sm[tid] += t;
        __syncthreads();
    }
    if (tid < NB_SCAN) bsum[tid] = sm[tid] - v;  // exclusive
}

__global__ void k_scanC(int* __restrict__ off, const int* __restrict__ bsum,
                        int* __restrict__ cur) {
    int i = blockIdx.x * 256 + threadIdx.x;
    if (i < NN) {
        int o = off[i] + bsum[i >> 9];
        off[i] = o;
        cur[i] = o;
    }
}

// packed CSR fill: one 8B store per edge {src, float_bits(w)}
__global__ void k_fill(const int* __restrict__ idx, const float* __restrict__ w,
                       int* __restrict__ cur, int2* __restrict__ epack) {
    int e = blockIdx.x * 256 + threadIdx.x;
    if (e >= EE) return;
    int c = idx[EE + e];
    int s = atomicAdd(&cur[c], 1);
    epack[s] = make_int2(idx[e], __float_as_int(w[e]));
}

__global__ void k_degdinv(const int* __restrict__ off, const int* __restrict__ cnt,
                          const int2* __restrict__ epack, float* __restrict__ dinv) {
    int n = blockIdx.x * 256 + threadIdx.x;
    if (n >= NN) return;
    int s0 = off[n], c = cnt[n];
    float d = 1.f;  // self loop
    for (int q = 0; q < c; q++) d += __int_as_float(epack[s0 + q].y);
    dinv[n] = rsqrtf(d);
}

// AX[b][n][t][f] = dinv[n]^2 * X[b][n][f][t] + sum_in nrm * X[b][src][f][t]
__global__ __launch_bounds__(64) void k_gather(const float* __restrict__ X,
                                               const float* __restrict__ dinv,
                                               const int2* __restrict__ epack,
                                               const int* __restrict__ off,
                                               const int* __restrict__ cnt,
                                               float* __restrict__ AX) {
    int tid = blockIdx.x * 64 + threadIdx.x;  // b*NN + n
    if (tid >= NNODES) return;
    int b = tid / NN;
    int n = tid - b * NN;
    float di = dinv[n];
    const float* Xb = X + (size_t)b * NN * 24;

    float xf[24], acc[24];
    {
        const float4* xs = (const float4*)(Xb + (size_t)n * 24);
        float s = di * di;
#pragma unroll
        for (int q = 0; q < 6; q++) {
            float4 v = xs[q];
            xf[4 * q] = v.x; xf[4 * q + 1] = v.y; xf[4 * q + 2] = v.z; xf[4 * q + 3] = v.w;
        }
#pragma unroll
        for (int t = 0; t < TT; t++) {
            acc[2 * t] = s * xf[t];
            acc[2 * t + 1] = s * xf[12 + t];
        }
    }
    int s0 = off[n], c = cnt[n];
    for (int q = 0; q < c; q++) {
        int2 ep = epack[s0 + q];
        int r = ep.x;
        float nrm = dinv[r] * __int_as_float(ep.y) * di;
        const float4* xr = (const float4*)(Xb + (size_t)r * 24);
#pragma unroll
        for (int p = 0; p < 6; p++) {
            float4 v = xr[p];
            xf[4 * p] = v.x; xf[4 * p + 1] = v.y; xf[4 * p + 2] = v.z; xf[4 * p + 3] = v.w;
        }
#pragma unroll
        for (int t = 0; t < TT; t++) {
            acc[2 * t] = fmaf(nrm, xf[t], acc[2 * t]);
            acc[2 * t + 1] = fmaf(nrm, xf[12 + t], acc[2 * t + 1]);
        }
    }
    float4* o = (float4*)(AX + (size_t)tid * 24);
#pragma unroll
    for (int q = 0; q < 6; q++)
        o[q] = make_float4(acc[4 * q], acc[4 * q + 1], acc[4 * q + 2], acc[4 * q + 3]);
}

// fold weights: per gate g at base g*1120: WF0[j]=sum_k W[0][k]Lw[k][j], WF1, cF, LB[k][j]=Lw[32+k][j]
__global__ void k_fold(const float* __restrict__ Wz, const float* __restrict__ bz,
                       const float* __restrict__ Lwz, const float* __restrict__ Lbz,
                       const float* __restrict__ Wr, const float* __restrict__ br,
                       const float* __restrict__ Lwr, const float* __restrict__ Lbr,
                       const float* __restrict__ Wh, const float* __restrict__ bh,
                       const float* __restrict__ Lwh, const float* __restrict__ Lbh,
                       const float* __restrict__ att, float* __restrict__ P) {
    int tid = threadIdx.x;
    if (tid < 96) {
        int g = tid >> 5, j = tid & 31;
        const float* W  = g == 0 ? Wz  : (g == 1 ? Wr  : Wh);
        const float* b  = g == 0 ? bz  : (g == 1 ? br  : bh);
        const float* Lw = g == 0 ? Lwz : (g == 1 ? Lwr : Lwh);
        const float* Lb = g == 0 ? Lbz : (g == 1 ? Lbr : Lbh);
        float* out = P + g * 1120;
        float w0 = 0.f, w1 = 0.f, c = 0.f;
        for (int k = 0; k < 32; k++) {
            float lw = Lw[k * 32 + j];
            w0 += W[k] * lw;
            w1 += W[32 + k] * lw;
            c  += b[k] * lw;
        }
        out[j] = w0;
        out[32 + j] = w1;
        out[64 + j] = c + Lb[j];
        for (int k = 0; k < 32; k++) out[96 + k * 32 + j] = Lw[(32 + k) * 32 + j];
    } else if (tid == 96) {
        float m = -1e30f;
        for (int t = 0; t < TT; t++) m = fmaxf(m, att[t]);
        float s = 0.f;
        float e[TT];
        for (int t = 0; t < TT; t++) { e[t] = __expf(att[t] - m); s += e[t]; }
        for (int t = 0; t < TT; t++) P[3360 + t] = e[t] / s;
    }
}

// Dual-node k-split recurrence: each wave owns node pair (2p, 2p+1) computed
// CONCURRENTLY — A and B dataflows are independent, so B's FMA tree issues
// under A's LDS/exp latency (intra-wave ILP halves exposed chain latency).
// lane=(h,j): 16-k weight strip per lane (48 VGPR) shared by both nodes.
// __launch_bounds__(256,2): 256-VGPR cap for the ~110-reg live set.
__global__ __launch_bounds__(256, 2) void k_recur(const float* __restrict__ AX,
                                                  const float* __restrict__ P,
                                                  float* __restrict__ out) {
    __shared__ __align__(16) float Hs[NW][2][32];
    __shared__ __align__(16) float rHs[NW][2][32];
    __shared__ __align__(16) float AXs[NW][48];
    const int lane = threadIdx.x & 63;
    const int w = threadIdx.x >> 6;
    const int j = lane & 31;
    const int h = lane >> 5;
    const int k0 = h * 16;
    const int pair = blockIdx.x * NW + w;
    if (pair >= NNODES / 2) return;

    // per-lane weight strip (loop-invariant): 16 k-values per gate
    float LBz[16], LBr[16], LBh[16];
    float wz0 = P[j],        wz1 = P[32 + j],        cz = P[64 + j];
    float wr0 = P[1120 + j], wr1 = P[1120 + 32 + j], cr = P[1120 + 64 + j];
    float wh0 = P[2240 + j], wh1 = P[2240 + 32 + j], ch = P[2240 + 64 + j];
#pragma unroll
    for (int k = 0; k < 16; k++) {
        LBz[k] = P[96 + (k0 + k) * 32 + j];
        LBr[k] = P[1120 + 96 + (k0 + k) * 32 + j];
        LBh[k] = P[2240 + 96 + (k0 + k) * 32 + j];
    }

    // stage both nodes' AX (48 contiguous floats)
    if (lane < 48) AXs[w][lane] = AX[(size_t)pair * 48 + lane];

    // t = 0: H == 0 -> z/h init-only, rH == 0.
    float2 aA = *(const float2*)&AXs[w][0];
    float2 aB = *(const float2*)&AXs[w][24];
    float zA = fsig(fmaf(aA.x, wz0, fmaf(aA.y, wz1, cz)));
    float zB = fsig(fmaf(aB.x, wz0, fmaf(aB.y, wz1, cz)));
    float thA = ftanh(fmaf(aA.x, wh0, fmaf(aA.y, wh1, ch)));
    float thB = ftanh(fmaf(aB.x, wh0, fmaf(aB.y, wh1, ch)));
    float HA = (1.f - zA) * thA;
    float HB = (1.f - zB) * thB;
    float p0 = P[3360];
    float accA = p0 * HA, accB = p0 * HB;
    if (lane < 32) { Hs[w][0][j] = HA; Hs[w][1][j] = HB; }

#pragma unroll 1
    for (int t = 1; t < TT; t++) {
        aA = *(const float2*)&AXs[w][2 * t];
        aB = *(const float2*)&AXs[w][24 + 2 * t];
        float hbA[16], hbB[16];
#pragma unroll
        for (int i = 0; i < 4; i++) {
            float4 vA = *(const float4*)&Hs[w][0][k0 + 4 * i];
            float4 vB = *(const float4*)&Hs[w][1][k0 + 4 * i];
            hbA[4 * i] = vA.x; hbA[4 * i + 1] = vA.y; hbA[4 * i + 2] = vA.z; hbA[4 * i + 3] = vA.w;
            hbB[4 * i] = vB.x; hbB[4 * i + 1] = vB.y; hbB[4 * i + 2] = vB.z; hbB[4 * i + 3] = vB.w;
        }
        // r gates (A,B interleaved)
        float srA, srB;
        {
            float a0 = 0.f, a1 = 0.f, b0 = 0.f, b1 = 0.f;
#pragma unroll
            for (int k = 0; k < 16; k += 2) {
                a0 = fmaf(hbA[k],     LBr[k],     a0);
                b0 = fmaf(hbB[k],     LBr[k],     b0);
                a1 = fmaf(hbA[k + 1], LBr[k + 1], a1);
                b1 = fmaf(hbB[k + 1], LBr[k + 1], b1);
            }
            srA = a0 + a1; srB = b0 + b1;
        }
        srA += __shfl_xor(srA, 32, 64);
        srB += __shfl_xor(srB, 32, 64);
        float rHA = fsig(fmaf(aA.x, wr0, fmaf(aA.y, wr1, cr)) + srA) * HA;
        float rHB = fsig(fmaf(aB.x, wr0, fmaf(aB.y, wr1, cr)) + srB) * HB;
        if (lane < 32) { rHs[w][0][j] = rHA; rHs[w][1][j] = rHB; }
        // z gates
        float szA, szB;
        {
            float a0 = 0.f, a1 = 0.f, b0 = 0.f, b1 = 0.f;
#pragma unroll
            for (int k = 0; k < 16; k += 2) {
                a0 = fmaf(hbA[k],     LBz[k],     a0);
                b0 = fmaf(hbB[k],     LBz[k],     b0);
                a1 = fmaf(hbA[k + 1], LBz[k + 1], a1);
                b1 = fmaf(hbB[k + 1], LBz[k + 1], b1);
            }
            szA = a0 + a1; szB = b0 + b1;
        }
        szA += __shfl_xor(szA, 32, 64);
        szB += __shfl_xor(szB, 32, 64);
        zA = fsig(fmaf(aA.x, wz0, fmaf(aA.y, wz1, cz)) + szA);
        zB = fsig(fmaf(aB.x, wz0, fmaf(aB.y, wz1, cz)) + szB);
        // h gates (read rH strips)
        float shA, shB;
        {
            float a0 = 0.f, a1 = 0.f, b0 = 0.f, b1 = 0.f;
#pragma unroll
            for (int i = 0; i < 4; i++) {
                float4 vA = *(const float4*)&rHs[w][0][k0 + 4 * i];
                float4 vB = *(const float4*)&rHs[w][1][k0 + 4 * i];
                a0 = fmaf(vA.x, LBh[4 * i],     a0);
                b0 = fmaf(vB.x, LBh[4 * i],     b0);
                a1 = fmaf(vA.y, LBh[4 * i + 1], a1);
                b1 = fmaf(vB.y, LBh[4 * i + 1], b1);
                a0 = fmaf(vA.z, LBh[4 * i + 2], a0);
                b0 = fmaf(vB.z, LBh[4 * i + 2], b0);
                a1 = fmaf(vA.w, LBh[4 * i + 3], a1);
                b1 = fmaf(vB.w, LBh[4 * i + 3], b1);
            }
            shA = a0 + a1; shB = b0 + b1;
        }
        shA += __shfl_xor(shA, 32, 64);
        shB += __shfl_xor(shB, 32, 64);
        thA = ftanh(fmaf(aA.x, wh0, fmaf(aA.y, wh1, ch)) + shA);
        thB = ftanh(fmaf(aB.x, wh0, fmaf(aB.y, wh1, ch)) + shB);
        float HnA = fmaf(zA, HA - thA, thA);
        float HnB = fmaf(zB, HB - thB, thB);
        HA = HnA; HB = HnB;
        float pt = P[3360 + t];
        accA = fmaf(pt, HnA, accA);
        accB = fmaf(pt, HnB, accB);
        if (lane < 32 && t < TT - 1) { Hs[w][0][j] = HnA; Hs[w][1][j] = HnB; }
    }
    if (lane < 32) {
        out[(size_t)pair * 64 + j] = accA;
        out[(size_t)pair * 64 + 32 + j] = accB;
    }
}

extern "C" void kernel_launch(void* const* d_in, const int* in_sizes, int n_in,
                              void* d_out, int out_size, void* d_ws, size_t ws_size,
                              hipStream_t stream) {
    const float* X   = (const float*)d_in[0];
    const int*   idx = (const int*)d_in[1];
    const float* ew  = (const float*)d_in[2];
    const float* Wz  = (const float*)d_in[3];
    const float* bz  = (const float*)d_in[4];
    const float* Wr  = (const float*)d_in[5];
    const float* br  = (const float*)d_in[6];
    const float* Wh  = (const float*)d_in[7];
    const float* bh  = (const float*)d_in[8];
    const float* Lwz = (const float*)d_in[9];
    const float* Lbz = (const float*)d_in[10];
    const float* Lwr = (const float*)d_in[11];
    const float* Lbr = (const float*)d_in[12];
    const float* Lwh = (const float*)d_in[13];
    const float* Lbh = (const float*)d_in[14];
    const float* att = (const float*)d_in[15];

    float* ws   = (float*)d_ws;
    float* dinv = ws;
    float* AX   = ws + OFF_AX;
    float* P    = ws + OFF_P;
    int*   cnt  = (int*)ws + OFF_CNT;
    int*   off  = (int*)ws + OFF_OFF;
    int*   cur  = (int*)ws + OFF_CUR;
    int*   bsum = (int*)ws + OFF_BSUM;
    float* out  = (float*)d_out;
    int2*  epack = (int2*)d_out;            // packed CSR scratch inside d_out

    hipMemsetAsync(cnt, 0, NN * sizeof(int), stream);
    hipLaunchKernelGGL(k_count, dim3((EE + 255) / 256), dim3(256), 0, stream, idx, cnt);
    hipLaunchKernelGGL(k_scanA, dim3(NB_SCAN), dim3(512), 0, stream, cnt, off, bsum);
    hipLaunchKernelGGL(k_scanB, dim3(1), dim3(128), 0, stream, bsum);
    hipLaunchKernelGGL(k_scanC, dim3((NN + 255) / 256), dim3(256), 0, stream, off, bsum, cur);
    hipLaunchKernelGGL(k_fill, dim3((EE + 255) / 256), dim3(256), 0, stream, idx, ew, cur, epack);
    hipLaunchKernelGGL(k_degdinv, dim3((NN + 255) / 256), dim3(256), 0, stream, off, cnt, epack, dinv);
    hipLaunchKernelGGL(k_gather, dim3((NNODES + 63) / 64), dim3(64), 0, stream,
                       X, dinv, epack, off, cnt, AX);
    hipLaunchKernelGGL(k_fold, dim3(1), dim3(128), 0, stream,
                       Wz, bz, Lwz, Lbz, Wr, br, Lwr, Lbr, Wh, bh, Lwh, Lbh, att, P);
    hipLaunchKernelGGL(k_recur, dim3(NBLK_REC), dim3(256), 0, stream, AX, P, out);
}